// Round 13
// baseline (165.628 us; speedup 1.0000x reference)
//
#include <hip/hip_runtime.h>
#include <hip/hip_bf16.h>

#define N_NODES 50000
#define NB 32
#define LN_EPS 1e-5f
#define SLOPE 0.2f

typedef __attribute__((ext_vector_type(8))) short bf16x8;
typedef __attribute__((ext_vector_type(4))) float f32x4;

__device__ __forceinline__ int imin(int a, int b){ return a < b ? a : b; }

__device__ __forceinline__ short f2bf(float f){
  union { float f; unsigned u; } v; v.f = f;
  unsigned r = v.u + 0x7fffu + ((v.u >> 16) & 1u);
  return (short)(r >> 16);
}

// 16-lane-group sum via COMPILER-VISIBLE DPP (update_dpp = v_mov_b32_dpp):
// unlike the R8 asm version (s_nop-stall pairs the compiler can't fill) and
// the R11 fused asm block (scheduling wall, -26us), the builtin lets the
// scheduler interleave the 8 independent reduction chains and MFMA/exp issue
// into the DPP hazard slots. row_ror ctrl = 0x120+n, rows are 16 lanes.
__device__ __forceinline__ float rsum16_b(float x){
  union { float f; int i; } u, v;
  u.f = x;
  v.i = __builtin_amdgcn_update_dpp(0, u.i, 0x128, 0xf, 0xf, false); u.f += v.f; // ror:8
  v.i = __builtin_amdgcn_update_dpp(0, u.i, 0x124, 0xf, 0xf, false); u.f += v.f; // ror:4
  v.i = __builtin_amdgcn_update_dpp(0, u.i, 0x122, 0xf, 0xf, false); u.f += v.f; // ror:2
  v.i = __builtin_amdgcn_update_dpp(0, u.i, 0x121, 0xf, 0xf, false); u.f += v.f; // ror:1
  return u.f;
}

__device__ __forceinline__ unsigned cvtpk(float a, float b){
  unsigned r;
  asm("v_cvt_pk_bf16_f32 %0, %1, %2" : "=v"(r) : "v"(a), "v"(b));
  return r;
}

__device__ __forceinline__ bf16x8 pack8(float4 a, float4 b){
  union { unsigned u[4]; bf16x8 v; } r;
  r.u[0] = cvtpk(a.x, a.y); r.u[1] = cvtpk(a.z, a.w);
  r.u[2] = cvtpk(b.x, b.y); r.u[3] = cvtpk(b.z, b.w);
  return r.v;
}

// packed weight fragment offsets in d_ws (ushort elements)
#define WKP 0          // [8 ks][8 nt][64 lane][8]
#define WVP 32768
#define WQP 65536      // [4 ks][8 nt][64 lane][8]
#define MLPP 81920

__global__ __launch_bounds__(256) void prep_pack(
    const float* __restrict__ wq, const float* __restrict__ wk,
    const float* __restrict__ wv, const float* __restrict__ mlp,
    unsigned short* __restrict__ wsP)
{
  int idx = blockIdx.x * 256 + threadIdx.x;
  const float* src; int base, K, local;
  if (idx < 32768)      { src = wk;  base = WKP;  local = idx;         K = 256; }
  else if (idx < 65536) { src = wv;  base = WVP;  local = idx - 32768; K = 256; }
  else if (idx < 81920) { src = wq;  base = WQP;  local = idx - 65536; K = 128; }
  else if (idx < 98304) { src = mlp; base = MLPP; local = idx - 81920; K = 128; }
  else return;
  int i  = local & 7;
  int l  = (local >> 3) & 63;
  int nt = (local >> 9) & 7;
  int ks = local >> 12;
  int row = nt * 16 + (l & 15);          // output channel (B col)
  int k   = ks * 32 + ((l >> 4) << 3) + i;
  wsP[base + local] = (unsigned short)f2bf(src[row * K + k]);
}

// stage one mail panel chunk: 8 mem_input floats (already in regs) + 8 cos feats
__device__ __forceinline__ void stage_write(
    unsigned short* sAp, const float* sTs, const float* sMts,
    const float* sTeW, const float* sTeB,
    float4 f0, float4 f1, int srow, int skc, int ssw, int sg, int m)
{
  float dt = sTs[srow] - sMts[srow*10 + m];
  const float4* tw = (const float4*)(sTeW + skc);
  const float4* tb = (const float4*)(sTeB + skc);
  float4 w0 = tw[0], w1 = tw[1];
  float4 b0 = tb[0], b1 = tb[1];
  float4 c0, c1;
  c0.x=__cosf(dt*w0.x+b0.x); c0.y=__cosf(dt*w0.y+b0.y); c0.z=__cosf(dt*w0.z+b0.z); c0.w=__cosf(dt*w0.w+b0.w);
  c1.x=__cosf(dt*w1.x+b1.x); c1.y=__cosf(dt*w1.y+b1.y); c1.z=__cosf(dt*w1.z+b1.z); c1.w=__cosf(dt*w1.w+b1.w);
  bf16x8* dst = (bf16x8*)sAp;
  dst[srow*32 + (sg ^ ssw)]      = pack8(f0, f1);
  dst[srow*32 + 16 + (sg ^ ssw)] = pack8(c0, c1);  // == (16+sg)^ssw since ssw<8
}

// launch_bounds 2nd arg = min BLOCKS/CU (confirmed R7/R8). (512,2) -> VGPR cap
// 128; kernel uses ~84, zero spill. R9 (3 blocks), R10 (2-mail ILP), R12
// (NB=64) all null/regressed -> this structure is the best found; only the
// in-loop reduction scheduling (this round) remained untested.
__global__ __launch_bounds__(512, 2) void fused_tmu(
    const float* __restrict__ mem, const float* __restrict__ mem_input,
    const float* __restrict__ ts, const float* __restrict__ mail_ts,
    const float* __restrict__ wq_b, const float* __restrict__ wk_b,
    const float* __restrict__ wv_b, const float* __restrict__ ln_g,
    const float* __restrict__ ln_b, const float* __restrict__ mlp_b,
    const float* __restrict__ te_w, const float* __restrict__ te_b,
    const unsigned short* __restrict__ wsP, float* __restrict__ out)
{
  __shared__ __align__(16) unsigned short sA[2 * NB * 256]; // two swizzled panels
  __shared__ float sTs[NB];
  __shared__ float sMts[NB * 10];
  __shared__ float sTeW[128], sTeB[128];
  __shared__ float sRed[NB * 16];

  const int tid  = threadIdx.x;
  const int lane = tid & 63;
  const int wid  = tid >> 6;         // 0..7 == head
  const int l15  = lane & 15;
  const int lg   = lane >> 4;
  const int node0 = blockIdx.x * NB;

  const int srow = tid >> 4;         // staging row 0..31 (16 threads/row)
  const int sg   = tid & 15;         // staging granule 0..15
  const int skc  = sg << 3;          // float col base
  const int sgn  = imin(node0 + srow, N_NODES - 1);
  const int ssw  = srow & 7;
  const float* miBase = mem_input + (size_t)sgn * 1280 + skc;

  // ---- prologue: issue loads (mem granule for Q panel, mail0 granule)
  float4 fm0, fm1, fa0, fa1;
  {
    const float4* mp = (const float4*)(mem + (size_t)sgn * 128 + skc);
    fm0 = mp[0]; fm1 = mp[1];
    const float4* mi0 = (const float4*)(miBase);
    fa0 = mi0[0]; fa1 = mi0[1];
  }

  if (tid < NB) sTs[tid] = ts[imin(node0 + tid, N_NODES - 1)];
  if (tid < 128){ sTeW[tid] = te_w[tid]; sTeB[tid] = te_b[tid]; }
  if (tid < NB * 10){
    int nn = tid / 10, mm = tid - nn * 10;
    sMts[tid] = mail_ts[(size_t)imin(node0 + nn, N_NODES - 1) * 10 + mm];
  }
  { // stage mem -> bf16 swizzled into panel 1 (granules 0..15; Q GEMM reads these)
    bf16x8* dst = (bf16x8*)sA;
    dst[NB*32 + srow*32 + (sg ^ ssw)] = pack8(fm0, fm1);
  }

  // per-lane channel c for this head
  const int c = wid * 16 + l15;
  float qb = wq_b[c], kb = wk_b[c], vb = wv_b[c];

  const bf16x8* wsv = (const bf16x8*)wsP;
  bf16x8 wqf[4];
  #pragma unroll
  for (int ks = 0; ks < 4; ks++)
    wqf[ks] = wsv[WQP/8 + (ks*8 + wid)*64 + lane];

  __syncthreads();   // sTs/sMts/te + panel 1 ready

  // stage mail 0 into panel 0; issue mail1 loads
  stage_write(sA, sTs, sMts, sTeW, sTeB, fa0, fa1, srow, skc, ssw, sg, 0);
  { const float4* mi1 = (const float4*)(miBase + 128); fa0 = mi1[0]; fa1 = mi1[1]; }

  // ---- Q GEMM from panel 1 (Q stays in registers, C-layout; qb folded via init)
  f32x4 z4 = {0.f, 0.f, 0.f, 0.f};
  f32x4 qac[2];
  qac[0] = (f32x4){qb, qb, qb, qb};
  qac[1] = qac[0];
  {
    const bf16x8* P1 = (const bf16x8*)sA + NB*32;
    #pragma unroll
    for (int ntr = 0; ntr < 2; ntr++){
      int r = ntr*16 + l15, rs = r & 7;
      #pragma unroll
      for (int ks = 0; ks < 4; ks++){
        bf16x8 af = P1[r*32 + ((ks*4 + lg) ^ rs)];
        qac[ntr] = __builtin_amdgcn_mfma_f32_16x16x32_bf16(af, wqf[ks], qac[ntr], 0, 0, 0);
      }
    }
  }

  // K and V weight fragments resident (1 head per wave: 64 VGPR total)
  bf16x8 wkf[8], wvf[8];
  #pragma unroll
  for (int ks = 0; ks < 8; ks++){
    wkf[ks] = wsv[WKP/8 + (ks*8 + wid)*64 + lane];
    wvf[ks] = wsv[WVP/8 + (ks*8 + wid)*64 + lane];
  }

  __syncthreads();   // panel 0 ready

  // ---- fused m-loop: compute m -> stage m+1 -> prefetch m+2 -> barrier
  f32x4 pv[2] = {z4, z4};
  f32x4 sm[2] = {z4, z4};
  for (int m = 0; m < 10; m++){
    const bf16x8* P = (const bf16x8*)sA + (m & 1) * NB*32;
    #pragma unroll
    for (int ntr = 0; ntr < 2; ntr++){
      int r = ntr*16 + l15, rs = r & 7;
      f32x4 ka = z4, va = z4;
      #pragma unroll
      for (int ks = 0; ks < 8; ks++){
        bf16x8 af = P[r*32 + ((ks*4 + lg) ^ rs)];
        ka = __builtin_amdgcn_mfma_f32_16x16x32_bf16(af, wkf[ks], ka, 0, 0, 0);
        va = __builtin_amdgcn_mfma_f32_16x16x32_bf16(af, wvf[ks], va, 0, 0, 0);
      }
      #pragma unroll
      for (int j = 0; j < 4; j++){
        float lv = (ka[j] + kb) * qac[ntr][j];
        lv = rsum16_b(lv);
        lv = fmaxf(lv, SLOPE * lv);
        lv = fminf(lv, 60.f);
        float p = __expf(lv);
        sm[ntr][j] += p;
        pv[ntr][j] += p * va[j];
      }
    }
    if (m < 9){
      stage_write(sA + ((m+1) & 1) * NB*256, sTs, sMts, sTeW, sTeB,
                  fa0, fa1, srow, skc, ssw, sg, m+1);
      if (m < 8){
        const float4* mi = (const float4*)(miBase + (size_t)(m+2)*128);
        fa0 = mi[0]; fa1 = mi[1];
      }
    }
    __syncthreads();
  }

  // ---- residual + LayerNorm
  float lgv = ln_g[c], lbv = ln_b[c], mbv = mlp_b[c];
  float rstv[2][4];
  #pragma unroll
  for (int ntr = 0; ntr < 2; ntr++)
    #pragma unroll
    for (int j = 0; j < 4; j++){
      int gn = imin(node0 + ntr*16 + lg*4 + j, N_NODES - 1);
      rstv[ntr][j] = pv[ntr][j] / sm[ntr][j] + vb + mem[(size_t)gn * 128 + c];
    }
  #pragma unroll
  for (int ntr = 0; ntr < 2; ntr++)
    #pragma unroll
    for (int j = 0; j < 4; j++){
      float s = rsum16_b(rstv[ntr][j]);
      float q = rsum16_b(rstv[ntr][j] * rstv[ntr][j]);
      if (l15 == 0){
        int nl = ntr*16 + lg*4 + j;
        sRed[nl*16 + wid*2    ] = s;
        sRed[nl*16 + wid*2 + 1] = q;
      }
    }
  __syncthreads();
  #pragma unroll
  for (int ntr = 0; ntr < 2; ntr++)
    #pragma unroll
    for (int j = 0; j < 4; j++){
      int nl = ntr*16 + lg*4 + j;
      float sum = 0.f, sq = 0.f;
      #pragma unroll
      for (int w = 0; w < 8; w++){
        sum += sRed[nl*16 + w*2];
        sq  += sRed[nl*16 + w*2 + 1];
      }
      float mu  = sum * (1.f/128.f);
      float var = sq * (1.f/128.f) - mu*mu;
      float rs  = rsqrtf(var + LN_EPS);
      float y = (rstv[ntr][j] - mu) * rs * lgv + lbv;
      sA[nl*256 + ((c >> 3) ^ (nl & 7))*8 + (c & 7)] = (unsigned short)f2bf(y);
    }

  bf16x8 mlpf[4];
  #pragma unroll
  for (int ks = 0; ks < 4; ks++)
    mlpf[ks] = wsv[MLPP/8 + (ks*8 + wid)*64 + lane];
  __syncthreads();

  // ---- MLP GEMM + ReLU + store (A = LN output in panel 0; mbv folded via init)
  f32x4 mac[2];
  mac[0] = (f32x4){mbv, mbv, mbv, mbv};
  mac[1] = mac[0];
  {
    const bf16x8* P0 = (const bf16x8*)sA;
    #pragma unroll
    for (int ntr = 0; ntr < 2; ntr++){
      int r = ntr*16 + l15, rs = r & 7;
      #pragma unroll
      for (int ks = 0; ks < 4; ks++){
        bf16x8 af = P0[r*32 + ((ks*4 + lg) ^ rs)];
        mac[ntr] = __builtin_amdgcn_mfma_f32_16x16x32_bf16(af, mlpf[ks], mac[ntr], 0, 0, 0);
      }
    }
  }
  #pragma unroll
  for (int ntr = 0; ntr < 2; ntr++)
    #pragma unroll
    for (int j = 0; j < 4; j++){
      float o = fmaxf(mac[ntr][j], 0.f);
      int node = node0 + ntr*16 + lg*4 + j;
      if (node < N_NODES)
        out[(size_t)node * 128 + c] = o;
    }
}

extern "C" void kernel_launch(void* const* d_in, const int* in_sizes, int n_in,
                              void* d_out, int out_size, void* d_ws, size_t ws_size,
                              hipStream_t stream)
{
  const float* mem       = (const float*)d_in[0];
  const float* mem_input = (const float*)d_in[1];
  const float* ts        = (const float*)d_in[2];
  const float* mail_ts   = (const float*)d_in[3];
  const float* wq_w      = (const float*)d_in[4];
  const float* wq_b      = (const float*)d_in[5];
  const float* wk_w      = (const float*)d_in[6];
  const float* wk_b      = (const float*)d_in[7];
  const float* wv_w      = (const float*)d_in[8];
  const float* wv_b      = (const float*)d_in[9];
  const float* ln_g      = (const float*)d_in[10];
  const float* ln_b      = (const float*)d_in[11];
  const float* mlp_w     = (const float*)d_in[12];
  const float* mlp_b     = (const float*)d_in[13];
  const float* te_w      = (const float*)d_in[14];
  const float* te_b      = (const float*)d_in[15];
  unsigned short* wsP = (unsigned short*)d_ws;
  float* outp = (float*)d_out;

  prep_pack<<<384, 256, 0, stream>>>(wq_w, wk_w, wv_w, mlp_w, wsP);
  int nblk = (N_NODES + NB - 1) / NB;
  fused_tmu<<<nblk, 512, 0, stream>>>(mem, mem_input, ts, mail_ts,
      wq_b, wk_b, wv_b, ln_g, ln_b, mlp_b, te_w, te_b, wsP, outp);
}

// Round 14
// 146.266 us; speedup vs baseline: 1.1324x; 1.1324x over previous
//
#include <hip/hip_runtime.h>
#include <hip/hip_bf16.h>

#define N_NODES 50000
#define NB 32
#define LN_EPS 1e-5f
#define SLOPE 0.2f

typedef __attribute__((ext_vector_type(8))) short bf16x8;
typedef __attribute__((ext_vector_type(4))) float f32x4;

__device__ __forceinline__ int imin(int a, int b){ return a < b ? a : b; }

__device__ __forceinline__ short f2bf(float f){
  union { float f; unsigned u; } v; v.f = f;
  unsigned r = v.u + 0x7fffu + ((v.u >> 16) & 1u);
  return (short)(r >> 16);
}

// all-lanes sum over each 16-lane group via DPP rotations (VALU-only, no DS).
// CDNA hazard: VALU-write -> DPP-read of same VGPR needs 2 wait states; the
// compiler cannot see inside asm, so guard every DPP with s_nop 1 explicitly.
// Keep the four small blocks SEPARATE and s_nop-guarded: R11 (one fused
// 17-instr block) and R13 (builtin mov_dpp+add) both regressed vs this form.
__device__ __forceinline__ float rsum16_dpp(float x){
  asm volatile(
    "s_nop 1\n\t"
    "v_add_f32_dpp %0, %0, %0 row_ror:8 row_mask:0xf bank_mask:0xf\n\t"
    "s_nop 1\n\t"
    "v_add_f32_dpp %0, %0, %0 row_ror:4 row_mask:0xf bank_mask:0xf\n\t"
    "s_nop 1\n\t"
    "v_add_f32_dpp %0, %0, %0 row_ror:2 row_mask:0xf bank_mask:0xf\n\t"
    "s_nop 1\n\t"
    "v_add_f32_dpp %0, %0, %0 row_ror:1 row_mask:0xf bank_mask:0xf"
    : "+v"(x));
  return x;
}

__device__ __forceinline__ unsigned cvtpk(float a, float b){
  unsigned r;
  asm("v_cvt_pk_bf16_f32 %0, %1, %2" : "=v"(r) : "v"(a), "v"(b));
  return r;
}

__device__ __forceinline__ bf16x8 pack8(float4 a, float4 b){
  union { unsigned u[4]; bf16x8 v; } r;
  r.u[0] = cvtpk(a.x, a.y); r.u[1] = cvtpk(a.z, a.w);
  r.u[2] = cvtpk(b.x, b.y); r.u[3] = cvtpk(b.z, b.w);
  return r.v;
}

// packed weight fragment offsets in d_ws (ushort elements)
#define WKP 0          // [8 ks][8 nt][64 lane][8]
#define WVP 32768
#define WQP 65536      // [4 ks][8 nt][64 lane][8]
#define MLPP 81920

__global__ __launch_bounds__(256) void prep_pack(
    const float* __restrict__ wq, const float* __restrict__ wk,
    const float* __restrict__ wv, const float* __restrict__ mlp,
    unsigned short* __restrict__ wsP)
{
  int idx = blockIdx.x * 256 + threadIdx.x;
  const float* src; int base, K, local;
  if (idx < 32768)      { src = wk;  base = WKP;  local = idx;         K = 256; }
  else if (idx < 65536) { src = wv;  base = WVP;  local = idx - 32768; K = 256; }
  else if (idx < 81920) { src = wq;  base = WQP;  local = idx - 65536; K = 128; }
  else if (idx < 98304) { src = mlp; base = MLPP; local = idx - 81920; K = 128; }
  else return;
  int i  = local & 7;
  int l  = (local >> 3) & 63;
  int nt = (local >> 9) & 7;
  int ks = local >> 12;
  int row = nt * 16 + (l & 15);          // output channel (B col)
  int k   = ks * 32 + ((l >> 4) << 3) + i;
  wsP[base + local] = (unsigned short)f2bf(src[row * K + k]);
}

// stage one mail panel chunk: 8 mem_input floats (already in regs) + 8 cos feats
__device__ __forceinline__ void stage_write(
    unsigned short* sAp, const float* sTs, const float* sMts,
    const float* sTeW, const float* sTeB,
    float4 f0, float4 f1, int srow, int skc, int ssw, int sg, int m)
{
  float dt = sTs[srow] - sMts[srow*10 + m];
  const float4* tw = (const float4*)(sTeW + skc);
  const float4* tb = (const float4*)(sTeB + skc);
  float4 w0 = tw[0], w1 = tw[1];
  float4 b0 = tb[0], b1 = tb[1];
  float4 c0, c1;
  c0.x=__cosf(dt*w0.x+b0.x); c0.y=__cosf(dt*w0.y+b0.y); c0.z=__cosf(dt*w0.z+b0.z); c0.w=__cosf(dt*w0.w+b0.w);
  c1.x=__cosf(dt*w1.x+b1.x); c1.y=__cosf(dt*w1.y+b1.y); c1.z=__cosf(dt*w1.z+b1.z); c1.w=__cosf(dt*w1.w+b1.w);
  bf16x8* dst = (bf16x8*)sAp;
  dst[srow*32 + (sg ^ ssw)]      = pack8(f0, f1);
  dst[srow*32 + 16 + (sg ^ ssw)] = pack8(c0, c1);  // == (16+sg)^ssw since ssw<8
}

// NOTE launch_bounds: hipcc's 2nd arg empirically behaves as min BLOCKS/CU
// (CUDA semantics): R7's (512,4) forced 8 waves/SIMD -> 64-VGPR cap -> 300MB
// scratch spill. (512,2) => 2 blocks/CU => 4 waves/SIMD => 128-VGPR cap,
// which this kernel's ~84-reg working set fits with zero spill.
// Final form: R9 (3 blocks/CU), R10 (2-mail ILP), R11/R13 (DPP scheduling
// variants), R12 (NB=64) all measured null or negative vs this structure.
__global__ __launch_bounds__(512, 2) void fused_tmu(
    const float* __restrict__ mem, const float* __restrict__ mem_input,
    const float* __restrict__ ts, const float* __restrict__ mail_ts,
    const float* __restrict__ wq_b, const float* __restrict__ wk_b,
    const float* __restrict__ wv_b, const float* __restrict__ ln_g,
    const float* __restrict__ ln_b, const float* __restrict__ mlp_b,
    const float* __restrict__ te_w, const float* __restrict__ te_b,
    const unsigned short* __restrict__ wsP, float* __restrict__ out)
{
  __shared__ __align__(16) unsigned short sA[2 * NB * 256]; // two swizzled panels
  __shared__ float sTs[NB];
  __shared__ float sMts[NB * 10];
  __shared__ float sTeW[128], sTeB[128];
  __shared__ float sRed[NB * 16];

  const int tid  = threadIdx.x;
  const int lane = tid & 63;
  const int wid  = tid >> 6;         // 0..7 == head
  const int l15  = lane & 15;
  const int lg   = lane >> 4;
  const int node0 = blockIdx.x * NB;

  const int srow = tid >> 4;         // staging row 0..31 (16 threads/row)
  const int sg   = tid & 15;         // staging granule 0..15
  const int skc  = sg << 3;          // float col base
  const int sgn  = imin(node0 + srow, N_NODES - 1);
  const int ssw  = srow & 7;
  const float* miBase = mem_input + (size_t)sgn * 1280 + skc;

  // ---- prologue: issue loads (mem granule for Q panel, mail0 granule)
  float4 fm0, fm1, fa0, fa1;
  {
    const float4* mp = (const float4*)(mem + (size_t)sgn * 128 + skc);
    fm0 = mp[0]; fm1 = mp[1];
    const float4* mi0 = (const float4*)(miBase);
    fa0 = mi0[0]; fa1 = mi0[1];
  }

  if (tid < NB) sTs[tid] = ts[imin(node0 + tid, N_NODES - 1)];
  if (tid < 128){ sTeW[tid] = te_w[tid]; sTeB[tid] = te_b[tid]; }
  if (tid < NB * 10){
    int nn = tid / 10, mm = tid - nn * 10;
    sMts[tid] = mail_ts[(size_t)imin(node0 + nn, N_NODES - 1) * 10 + mm];
  }
  { // stage mem -> bf16 swizzled into panel 1 (granules 0..15; Q GEMM reads these)
    bf16x8* dst = (bf16x8*)sA;
    dst[NB*32 + srow*32 + (sg ^ ssw)] = pack8(fm0, fm1);
  }

  // per-lane channel c for this head
  const int c = wid * 16 + l15;
  float qb = wq_b[c], kb = wk_b[c], vb = wv_b[c];

  const bf16x8* wsv = (const bf16x8*)wsP;
  bf16x8 wqf[4];
  #pragma unroll
  for (int ks = 0; ks < 4; ks++)
    wqf[ks] = wsv[WQP/8 + (ks*8 + wid)*64 + lane];

  __syncthreads();   // sTs/sMts/te + panel 1 ready

  // stage mail 0 into panel 0; issue mail1 loads
  stage_write(sA, sTs, sMts, sTeW, sTeB, fa0, fa1, srow, skc, ssw, sg, 0);
  { const float4* mi1 = (const float4*)(miBase + 128); fa0 = mi1[0]; fa1 = mi1[1]; }

  // ---- Q GEMM from panel 1 (Q stays in registers, C-layout; qb folded via init)
  f32x4 z4 = {0.f, 0.f, 0.f, 0.f};
  f32x4 qac[2];
  qac[0] = (f32x4){qb, qb, qb, qb};
  qac[1] = qac[0];
  {
    const bf16x8* P1 = (const bf16x8*)sA + NB*32;
    #pragma unroll
    for (int ntr = 0; ntr < 2; ntr++){
      int r = ntr*16 + l15, rs = r & 7;
      #pragma unroll
      for (int ks = 0; ks < 4; ks++){
        bf16x8 af = P1[r*32 + ((ks*4 + lg) ^ rs)];
        qac[ntr] = __builtin_amdgcn_mfma_f32_16x16x32_bf16(af, wqf[ks], qac[ntr], 0, 0, 0);
      }
    }
  }

  // K and V weight fragments resident (1 head per wave: 64 VGPR total)
  bf16x8 wkf[8], wvf[8];
  #pragma unroll
  for (int ks = 0; ks < 8; ks++){
    wkf[ks] = wsv[WKP/8 + (ks*8 + wid)*64 + lane];
    wvf[ks] = wsv[WVP/8 + (ks*8 + wid)*64 + lane];
  }

  __syncthreads();   // panel 0 ready

  // ---- fused m-loop: compute m -> stage m+1 -> prefetch m+2 -> barrier
  f32x4 pv[2] = {z4, z4};
  f32x4 sm[2] = {z4, z4};
  for (int m = 0; m < 10; m++){
    const bf16x8* P = (const bf16x8*)sA + (m & 1) * NB*32;
    #pragma unroll
    for (int ntr = 0; ntr < 2; ntr++){
      int r = ntr*16 + l15, rs = r & 7;
      f32x4 ka = z4, va = z4;
      #pragma unroll
      for (int ks = 0; ks < 8; ks++){
        bf16x8 af = P[r*32 + ((ks*4 + lg) ^ rs)];
        ka = __builtin_amdgcn_mfma_f32_16x16x32_bf16(af, wkf[ks], ka, 0, 0, 0);
        va = __builtin_amdgcn_mfma_f32_16x16x32_bf16(af, wvf[ks], va, 0, 0, 0);
      }
      #pragma unroll
      for (int j = 0; j < 4; j++){
        float lv = (ka[j] + kb) * qac[ntr][j];
        lv = rsum16_dpp(lv);
        lv = fmaxf(lv, SLOPE * lv);
        lv = fminf(lv, 60.f);
        float p = __expf(lv);
        sm[ntr][j] += p;
        pv[ntr][j] += p * va[j];
      }
    }
    if (m < 9){
      stage_write(sA + ((m+1) & 1) * NB*256, sTs, sMts, sTeW, sTeB,
                  fa0, fa1, srow, skc, ssw, sg, m+1);
      if (m < 8){
        const float4* mi = (const float4*)(miBase + (size_t)(m+2)*128);
        fa0 = mi[0]; fa1 = mi[1];
      }
    }
    __syncthreads();
  }

  // ---- residual + LayerNorm
  float lgv = ln_g[c], lbv = ln_b[c], mbv = mlp_b[c];
  float rstv[2][4];
  #pragma unroll
  for (int ntr = 0; ntr < 2; ntr++)
    #pragma unroll
    for (int j = 0; j < 4; j++){
      int gn = imin(node0 + ntr*16 + lg*4 + j, N_NODES - 1);
      rstv[ntr][j] = pv[ntr][j] / sm[ntr][j] + vb + mem[(size_t)gn * 128 + c];
    }
  #pragma unroll
  for (int ntr = 0; ntr < 2; ntr++)
    #pragma unroll
    for (int j = 0; j < 4; j++){
      float s = rsum16_dpp(rstv[ntr][j]);
      float q = rsum16_dpp(rstv[ntr][j] * rstv[ntr][j]);
      if (l15 == 0){
        int nl = ntr*16 + lg*4 + j;
        sRed[nl*16 + wid*2    ] = s;
        sRed[nl*16 + wid*2 + 1] = q;
      }
    }
  __syncthreads();
  #pragma unroll
  for (int ntr = 0; ntr < 2; ntr++)
    #pragma unroll
    for (int j = 0; j < 4; j++){
      int nl = ntr*16 + lg*4 + j;
      float sum = 0.f, sq = 0.f;
      #pragma unroll
      for (int w = 0; w < 8; w++){
        sum += sRed[nl*16 + w*2];
        sq  += sRed[nl*16 + w*2 + 1];
      }
      float mu  = sum * (1.f/128.f);
      float var = sq * (1.f/128.f) - mu*mu;
      float rs  = rsqrtf(var + LN_EPS);
      float y = (rstv[ntr][j] - mu) * rs * lgv + lbv;
      sA[nl*256 + ((c >> 3) ^ (nl & 7))*8 + (c & 7)] = (unsigned short)f2bf(y);
    }

  bf16x8 mlpf[4];
  #pragma unroll
  for (int ks = 0; ks < 4; ks++)
    mlpf[ks] = wsv[MLPP/8 + (ks*8 + wid)*64 + lane];
  __syncthreads();

  // ---- MLP GEMM + ReLU + store (A = LN output in panel 0; mbv folded via init)
  f32x4 mac[2];
  mac[0] = (f32x4){mbv, mbv, mbv, mbv};
  mac[1] = mac[0];
  {
    const bf16x8* P0 = (const bf16x8*)sA;
    #pragma unroll
    for (int ntr = 0; ntr < 2; ntr++){
      int r = ntr*16 + l15, rs = r & 7;
      #pragma unroll
      for (int ks = 0; ks < 4; ks++){
        bf16x8 af = P0[r*32 + ((ks*4 + lg) ^ rs)];
        mac[ntr] = __builtin_amdgcn_mfma_f32_16x16x32_bf16(af, mlpf[ks], mac[ntr], 0, 0, 0);
      }
    }
  }
  #pragma unroll
  for (int ntr = 0; ntr < 2; ntr++)
    #pragma unroll
    for (int j = 0; j < 4; j++){
      float o = fmaxf(mac[ntr][j], 0.f);
      int node = node0 + ntr*16 + lg*4 + j;
      if (node < N_NODES)
        out[(size_t)node * 128 + c] = o;
    }
}

extern "C" void kernel_launch(void* const* d_in, const int* in_sizes, int n_in,
                              void* d_out, int out_size, void* d_ws, size_t ws_size,
                              hipStream_t stream)
{
  const float* mem       = (const float*)d_in[0];
  const float* mem_input = (const float*)d_in[1];
  const float* ts        = (const float*)d_in[2];
  const float* mail_ts   = (const float*)d_in[3];
  const float* wq_w      = (const float*)d_in[4];
  const float* wq_b      = (const float*)d_in[5];
  const float* wk_w      = (const float*)d_in[6];
  const float* wk_b      = (const float*)d_in[7];
  const float* wv_w      = (const float*)d_in[8];
  const float* wv_b      = (const float*)d_in[9];
  const float* ln_g      = (const float*)d_in[10];
  const float* ln_b      = (const float*)d_in[11];
  const float* mlp_w     = (const float*)d_in[12];
  const float* mlp_b     = (const float*)d_in[13];
  const float* te_w      = (const float*)d_in[14];
  const float* te_b      = (const float*)d_in[15];
  unsigned short* wsP = (unsigned short*)d_ws;
  float* outp = (float*)d_out;

  prep_pack<<<384, 256, 0, stream>>>(wq_w, wk_w, wv_w, mlp_w, wsP);
  int nblk = (N_NODES + NB - 1) / NB;
  fused_tmu<<<nblk, 512, 0, stream>>>(mem, mem_input, ts, mail_ts,
      wq_b, wk_b, wv_b, ln_g, ln_b, mlp_b, te_w, te_b, wsP, outp);
}

// Round 15
// 135.331 us; speedup vs baseline: 1.2239x; 1.0808x over previous
//
#include <hip/hip_runtime.h>
#include <hip/hip_bf16.h>

#define N_NODES 50000
#define NB 32
#define NTILES 1563          // ceil(50000/32)
#define PGRID 512            // persistent grid: 2 blocks/CU x 256 CU
#define LN_EPS 1e-5f
#define SLOPE 0.2f

typedef __attribute__((ext_vector_type(8))) short bf16x8;
typedef __attribute__((ext_vector_type(4))) float f32x4;

__device__ __forceinline__ int imin(int a, int b){ return a < b ? a : b; }

__device__ __forceinline__ short f2bf(float f){
  union { float f; unsigned u; } v; v.f = f;
  unsigned r = v.u + 0x7fffu + ((v.u >> 16) & 1u);
  return (short)(r >> 16);
}

// all-lanes sum over each 16-lane group via DPP rotations (VALU-only, no DS).
// CDNA hazard: VALU-write -> DPP-read of same VGPR needs 2 wait states; the
// compiler cannot see inside asm, so guard every DPP with s_nop 1 explicitly.
// Keep the four small blocks SEPARATE and s_nop-guarded: R11 (one fused
// 17-instr block) and R13 (builtin mov_dpp+add) both regressed vs this form.
__device__ __forceinline__ float rsum16_dpp(float x){
  asm volatile(
    "s_nop 1\n\t"
    "v_add_f32_dpp %0, %0, %0 row_ror:8 row_mask:0xf bank_mask:0xf\n\t"
    "s_nop 1\n\t"
    "v_add_f32_dpp %0, %0, %0 row_ror:4 row_mask:0xf bank_mask:0xf\n\t"
    "s_nop 1\n\t"
    "v_add_f32_dpp %0, %0, %0 row_ror:2 row_mask:0xf bank_mask:0xf\n\t"
    "s_nop 1\n\t"
    "v_add_f32_dpp %0, %0, %0 row_ror:1 row_mask:0xf bank_mask:0xf"
    : "+v"(x));
  return x;
}

__device__ __forceinline__ unsigned cvtpk(float a, float b){
  unsigned r;
  asm("v_cvt_pk_bf16_f32 %0, %1, %2" : "=v"(r) : "v"(a), "v"(b));
  return r;
}

__device__ __forceinline__ bf16x8 pack8(float4 a, float4 b){
  union { unsigned u[4]; bf16x8 v; } r;
  r.u[0] = cvtpk(a.x, a.y); r.u[1] = cvtpk(a.z, a.w);
  r.u[2] = cvtpk(b.x, b.y); r.u[3] = cvtpk(b.z, b.w);
  return r.v;
}

// packed weight fragment offsets in d_ws (ushort elements)
#define WKP 0          // [8 ks][8 nt][64 lane][8]
#define WVP 32768
#define WQP 65536      // [4 ks][8 nt][64 lane][8]
#define MLPP 81920

__global__ __launch_bounds__(256) void prep_pack(
    const float* __restrict__ wq, const float* __restrict__ wk,
    const float* __restrict__ wv, const float* __restrict__ mlp,
    unsigned short* __restrict__ wsP)
{
  int idx = blockIdx.x * 256 + threadIdx.x;
  const float* src; int base, K, local;
  if (idx < 32768)      { src = wk;  base = WKP;  local = idx;         K = 256; }
  else if (idx < 65536) { src = wv;  base = WVP;  local = idx - 32768; K = 256; }
  else if (idx < 81920) { src = wq;  base = WQP;  local = idx - 65536; K = 128; }
  else if (idx < 98304) { src = mlp; base = MLPP; local = idx - 81920; K = 128; }
  else return;
  int i  = local & 7;
  int l  = (local >> 3) & 63;
  int nt = (local >> 9) & 7;
  int ks = local >> 12;
  int row = nt * 16 + (l & 15);          // output channel (B col)
  int k   = ks * 32 + ((l >> 4) << 3) + i;
  wsP[base + local] = (unsigned short)f2bf(src[row * K + k]);
}

// stage one mail panel chunk: 8 mem_input floats (already in regs) + 8 cos feats
__device__ __forceinline__ void stage_write(
    unsigned short* sAp, const float* sTs, const float* sMts,
    const float* sTeW, const float* sTeB,
    float4 f0, float4 f1, int srow, int skc, int ssw, int sg, int m)
{
  float dt = sTs[srow] - sMts[srow*10 + m];
  const float4* tw = (const float4*)(sTeW + skc);
  const float4* tb = (const float4*)(sTeB + skc);
  float4 w0 = tw[0], w1 = tw[1];
  float4 b0 = tb[0], b1 = tb[1];
  float4 c0, c1;
  c0.x=__cosf(dt*w0.x+b0.x); c0.y=__cosf(dt*w0.y+b0.y); c0.z=__cosf(dt*w0.z+b0.z); c0.w=__cosf(dt*w0.w+b0.w);
  c1.x=__cosf(dt*w1.x+b1.x); c1.y=__cosf(dt*w1.y+b1.y); c1.z=__cosf(dt*w1.z+b1.z); c1.w=__cosf(dt*w1.w+b1.w);
  bf16x8* dst = (bf16x8*)sAp;
  dst[srow*32 + (sg ^ ssw)]      = pack8(f0, f1);
  dst[srow*32 + 16 + (sg ^ ssw)] = pack8(c0, c1);  // == (16+sg)^ssw since ssw<8
}

// Persistent-grid variant of the verified R8 kernel: 512 blocks (2/CU), each
// loops tiles tb, tb+512, ... Weight fragments (wkf/wvf) loaded ONCE per
// block instead of once per tile (3x less L2 weight traffic + vmcnt waits);
// 2/3 fewer dispatches; smoother tail. Tile seam audited race-free: next
// tile's sTs/sMts/panel-1 writes are >=2 barriers after their last readers,
// and panel-0 writes are ordered by the next tile's own prologue barrier.
__global__ __launch_bounds__(512, 2) void fused_tmu(
    const float* __restrict__ mem, const float* __restrict__ mem_input,
    const float* __restrict__ ts, const float* __restrict__ mail_ts,
    const float* __restrict__ wq_b, const float* __restrict__ wk_b,
    const float* __restrict__ wv_b, const float* __restrict__ ln_g,
    const float* __restrict__ ln_b, const float* __restrict__ mlp_b,
    const float* __restrict__ te_w, const float* __restrict__ te_b,
    const unsigned short* __restrict__ wsP, float* __restrict__ out)
{
  __shared__ __align__(16) unsigned short sA[2 * NB * 256]; // two swizzled panels
  __shared__ float sTs[NB];
  __shared__ float sMts[NB * 10];
  __shared__ float sTeW[128], sTeB[128];
  __shared__ float sRed[NB * 16];

  const int tid  = threadIdx.x;
  const int lane = tid & 63;
  const int wid  = tid >> 6;         // 0..7 == head
  const int l15  = lane & 15;
  const int lg   = lane >> 4;

  const int srow = tid >> 4;         // staging row 0..31 (16 threads/row)
  const int sg   = tid & 15;         // staging granule 0..15
  const int skc  = sg << 3;          // float col base
  const int ssw  = srow & 7;

  // ---- block-invariant setup (once per persistent block)
  if (tid < 128){ sTeW[tid] = te_w[tid]; sTeB[tid] = te_b[tid]; }

  const int c = wid * 16 + l15;      // per-lane channel for this head
  float qb = wq_b[c], kb = wk_b[c], vb = wv_b[c];
  float lgv = ln_g[c], lbv = ln_b[c], mbv = mlp_b[c];

  const bf16x8* wsv = (const bf16x8*)wsP;
  // K and V weight fragments resident for the whole block (64 VGPR)
  bf16x8 wkf[8], wvf[8];
  #pragma unroll
  for (int ks = 0; ks < 8; ks++){
    wkf[ks] = wsv[WKP/8 + (ks*8 + wid)*64 + lane];
    wvf[ks] = wsv[WVP/8 + (ks*8 + wid)*64 + lane];
  }

  f32x4 z4 = {0.f, 0.f, 0.f, 0.f};

  for (int tb = blockIdx.x; tb < NTILES; tb += PGRID){
    const int node0 = tb * NB;
    const int sgn = imin(node0 + srow, N_NODES - 1);
    const float* miBase = mem_input + (size_t)sgn * 1280 + skc;

    // ---- per-tile prologue: issue loads (mem granule, mail0 granule)
    float4 fm0, fm1, fa0, fa1;
    {
      const float4* mp = (const float4*)(mem + (size_t)sgn * 128 + skc);
      fm0 = mp[0]; fm1 = mp[1];
      const float4* mi0 = (const float4*)(miBase);
      fa0 = mi0[0]; fa1 = mi0[1];
    }
    if (tid < NB) sTs[tid] = ts[imin(node0 + tid, N_NODES - 1)];
    if (tid < NB * 10){
      int nn = tid / 10, mm = tid - nn * 10;
      sMts[tid] = mail_ts[(size_t)imin(node0 + nn, N_NODES - 1) * 10 + mm];
    }
    { // stage mem -> bf16 swizzled into panel 1 (Q GEMM reads these)
      bf16x8* dst = (bf16x8*)sA;
      dst[NB*32 + srow*32 + (sg ^ ssw)] = pack8(fm0, fm1);
    }
    bf16x8 wqf[4];
    #pragma unroll
    for (int ks = 0; ks < 4; ks++)
      wqf[ks] = wsv[WQP/8 + (ks*8 + wid)*64 + lane];

    __syncthreads();   // sTs/sMts(/te on first tile) + panel 1 ready

    // stage mail 0 into panel 0; issue mail1 loads
    stage_write(sA, sTs, sMts, sTeW, sTeB, fa0, fa1, srow, skc, ssw, sg, 0);
    { const float4* mi1 = (const float4*)(miBase + 128); fa0 = mi1[0]; fa1 = mi1[1]; }

    // ---- Q GEMM from panel 1 (Q in registers, C-layout; qb folded via init)
    f32x4 qac[2];
    qac[0] = (f32x4){qb, qb, qb, qb};
    qac[1] = qac[0];
    {
      const bf16x8* P1 = (const bf16x8*)sA + NB*32;
      #pragma unroll
      for (int ntr = 0; ntr < 2; ntr++){
        int r = ntr*16 + l15, rs = r & 7;
        #pragma unroll
        for (int ks = 0; ks < 4; ks++){
          bf16x8 af = P1[r*32 + ((ks*4 + lg) ^ rs)];
          qac[ntr] = __builtin_amdgcn_mfma_f32_16x16x32_bf16(af, wqf[ks], qac[ntr], 0, 0, 0);
        }
      }
    }

    __syncthreads();   // panel 0 ready

    // ---- fused m-loop: compute m -> stage m+1 -> prefetch m+2 -> barrier
    f32x4 pv[2] = {z4, z4};
    f32x4 sm[2] = {z4, z4};
    for (int m = 0; m < 10; m++){
      const bf16x8* P = (const bf16x8*)sA + (m & 1) * NB*32;
      #pragma unroll
      for (int ntr = 0; ntr < 2; ntr++){
        int r = ntr*16 + l15, rs = r & 7;
        f32x4 ka = z4, va = z4;
        #pragma unroll
        for (int ks = 0; ks < 8; ks++){
          bf16x8 af = P[r*32 + ((ks*4 + lg) ^ rs)];
          ka = __builtin_amdgcn_mfma_f32_16x16x32_bf16(af, wkf[ks], ka, 0, 0, 0);
          va = __builtin_amdgcn_mfma_f32_16x16x32_bf16(af, wvf[ks], va, 0, 0, 0);
        }
        #pragma unroll
        for (int j = 0; j < 4; j++){
          float lv = (ka[j] + kb) * qac[ntr][j];
          lv = rsum16_dpp(lv);
          lv = fmaxf(lv, SLOPE * lv);
          lv = fminf(lv, 60.f);
          float p = __expf(lv);
          sm[ntr][j] += p;
          pv[ntr][j] += p * va[j];
        }
      }
      if (m < 9){
        stage_write(sA + ((m+1) & 1) * NB*256, sTs, sMts, sTeW, sTeB,
                    fa0, fa1, srow, skc, ssw, sg, m+1);
        if (m < 8){
          const float4* mi = (const float4*)(miBase + (size_t)(m+2)*128);
          fa0 = mi[0]; fa1 = mi[1];
        }
      }
      __syncthreads();
    }

    // ---- residual + LayerNorm
    float rstv[2][4];
    #pragma unroll
    for (int ntr = 0; ntr < 2; ntr++)
      #pragma unroll
      for (int j = 0; j < 4; j++){
        int gn = imin(node0 + ntr*16 + lg*4 + j, N_NODES - 1);
        rstv[ntr][j] = pv[ntr][j] / sm[ntr][j] + vb + mem[(size_t)gn * 128 + c];
      }
    #pragma unroll
    for (int ntr = 0; ntr < 2; ntr++)
      #pragma unroll
      for (int j = 0; j < 4; j++){
        float s = rsum16_dpp(rstv[ntr][j]);
        float q = rsum16_dpp(rstv[ntr][j] * rstv[ntr][j]);
        if (l15 == 0){
          int nl = ntr*16 + lg*4 + j;
          sRed[nl*16 + wid*2    ] = s;
          sRed[nl*16 + wid*2 + 1] = q;
        }
      }
    __syncthreads();
    #pragma unroll
    for (int ntr = 0; ntr < 2; ntr++)
      #pragma unroll
      for (int j = 0; j < 4; j++){
        int nl = ntr*16 + lg*4 + j;
        float sum = 0.f, sq = 0.f;
        #pragma unroll
        for (int w = 0; w < 8; w++){
          sum += sRed[nl*16 + w*2];
          sq  += sRed[nl*16 + w*2 + 1];
        }
        float mu  = sum * (1.f/128.f);
        float var = sq * (1.f/128.f) - mu*mu;
        float rs  = rsqrtf(var + LN_EPS);
        float y = (rstv[ntr][j] - mu) * rs * lgv + lbv;
        sA[nl*256 + ((c >> 3) ^ (nl & 7))*8 + (c & 7)] = (unsigned short)f2bf(y);
      }

    bf16x8 mlpf[4];
    #pragma unroll
    for (int ks = 0; ks < 4; ks++)
      mlpf[ks] = wsv[MLPP/8 + (ks*8 + wid)*64 + lane];
    __syncthreads();

    // ---- MLP GEMM + ReLU + store (A = LN output in panel 0; mbv folded)
    f32x4 mac[2];
    mac[0] = (f32x4){mbv, mbv, mbv, mbv};
    mac[1] = mac[0];
    {
      const bf16x8* P0 = (const bf16x8*)sA;
      #pragma unroll
      for (int ntr = 0; ntr < 2; ntr++){
        int r = ntr*16 + l15, rs = r & 7;
        #pragma unroll
        for (int ks = 0; ks < 4; ks++){
          bf16x8 af = P0[r*32 + ((ks*4 + lg) ^ rs)];
          mac[ntr] = __builtin_amdgcn_mfma_f32_16x16x32_bf16(af, mlpf[ks], mac[ntr], 0, 0, 0);
        }
      }
    }
    #pragma unroll
    for (int ntr = 0; ntr < 2; ntr++)
      #pragma unroll
      for (int j = 0; j < 4; j++){
        float o = fmaxf(mac[ntr][j], 0.f);
        int node = node0 + ntr*16 + lg*4 + j;
        if (node < N_NODES)
          out[(size_t)node * 128 + c] = o;
      }
    // no trailing barrier needed: next tile's panel-0 write is ordered by its
    // own prologue barrier; sTs/sMts/panel-1 writes conflict with nothing
    // after the m-loop's final barrier.
  }
}

extern "C" void kernel_launch(void* const* d_in, const int* in_sizes, int n_in,
                              void* d_out, int out_size, void* d_ws, size_t ws_size,
                              hipStream_t stream)
{
  const float* mem       = (const float*)d_in[0];
  const float* mem_input = (const float*)d_in[1];
  const float* ts        = (const float*)d_in[2];
  const float* mail_ts   = (const float*)d_in[3];
  const float* wq_w      = (const float*)d_in[4];
  const float* wq_b      = (const float*)d_in[5];
  const float* wk_w      = (const float*)d_in[6];
  const float* wk_b      = (const float*)d_in[7];
  const float* wv_w      = (const float*)d_in[8];
  const float* wv_b      = (const float*)d_in[9];
  const float* ln_g      = (const float*)d_in[10];
  const float* ln_b      = (const float*)d_in[11];
  const float* mlp_w     = (const float*)d_in[12];
  const float* mlp_b     = (const float*)d_in[13];
  const float* te_w      = (const float*)d_in[14];
  const float* te_b      = (const float*)d_in[15];
  unsigned short* wsP = (unsigned short*)d_ws;
  float* outp = (float*)d_out;

  prep_pack<<<384, 256, 0, stream>>>(wq_w, wk_w, wv_w, mlp_w, wsP);
  fused_tmu<<<PGRID, 512, 0, stream>>>(mem, mem_input, ts, mail_ts,
      wq_b, wk_b, wv_b, ln_g, ln_b, mlp_b, te_w, te_b, wsP, outp);
}

// Round 16
// 134.914 us; speedup vs baseline: 1.2277x; 1.0031x over previous
//
#include <hip/hip_runtime.h>
#include <hip/hip_bf16.h>

#define N_NODES 50000
#define NB 32
#define NTILES 1563          // ceil(50000/32)
#define PGRID 512            // persistent grid: 2 blocks/CU x 256 CU
#define LN_EPS 1e-5f
#define SLOPE 0.2f

typedef __attribute__((ext_vector_type(8))) short bf16x8;
typedef __attribute__((ext_vector_type(4))) float f32x4;

__device__ __forceinline__ int imin(int a, int b){ return a < b ? a : b; }

__device__ __forceinline__ short f2bf(float f){
  union { float f; unsigned u; } v; v.f = f;
  unsigned r = v.u + 0x7fffu + ((v.u >> 16) & 1u);
  return (short)(r >> 16);
}

// all-lanes sum over each 16-lane group via DPP rotations (VALU-only, no DS).
// CDNA hazard: VALU-write -> DPP-read needs 2 wait states; compiler can't see
// inside asm, so each DPP is s_nop-guarded. Keep the four small blocks
// SEPARATE: R11 (fused block) and R13 (builtin form) both regressed.
__device__ __forceinline__ float rsum16_dpp(float x){
  asm volatile(
    "s_nop 1\n\t"
    "v_add_f32_dpp %0, %0, %0 row_ror:8 row_mask:0xf bank_mask:0xf\n\t"
    "s_nop 1\n\t"
    "v_add_f32_dpp %0, %0, %0 row_ror:4 row_mask:0xf bank_mask:0xf\n\t"
    "s_nop 1\n\t"
    "v_add_f32_dpp %0, %0, %0 row_ror:2 row_mask:0xf bank_mask:0xf\n\t"
    "s_nop 1\n\t"
    "v_add_f32_dpp %0, %0, %0 row_ror:1 row_mask:0xf bank_mask:0xf"
    : "+v"(x));
  return x;
}

__device__ __forceinline__ unsigned cvtpk(float a, float b){
  unsigned r;
  asm("v_cvt_pk_bf16_f32 %0, %1, %2" : "=v"(r) : "v"(a), "v"(b));
  return r;
}

__device__ __forceinline__ bf16x8 pack8(float4 a, float4 b){
  union { unsigned u[4]; bf16x8 v; } r;
  r.u[0] = cvtpk(a.x, a.y); r.u[1] = cvtpk(a.z, a.w);
  r.u[2] = cvtpk(b.x, b.y); r.u[3] = cvtpk(b.z, b.w);
  return r.v;
}

// packed weight fragment offsets in d_ws (ushort elements)
#define WKP 0          // [8 ks][8 nt][64 lane][8]
#define WVP 32768
#define WQP 65536      // [4 ks][8 nt][64 lane][8]
#define MLPP 81920

__global__ __launch_bounds__(256) void prep_pack(
    const float* __restrict__ wq, const float* __restrict__ wk,
    const float* __restrict__ wv, const float* __restrict__ mlp,
    unsigned short* __restrict__ wsP)
{
  int idx = blockIdx.x * 256 + threadIdx.x;
  const float* src; int base, K, local;
  if (idx < 32768)      { src = wk;  base = WKP;  local = idx;         K = 256; }
  else if (idx < 65536) { src = wv;  base = WVP;  local = idx - 32768; K = 256; }
  else if (idx < 81920) { src = wq;  base = WQP;  local = idx - 65536; K = 128; }
  else if (idx < 98304) { src = mlp; base = MLPP; local = idx - 81920; K = 128; }
  else return;
  int i  = local & 7;
  int l  = (local >> 3) & 63;
  int nt = (local >> 9) & 7;
  int ks = local >> 12;
  int row = nt * 16 + (l & 15);          // output channel (B col)
  int k   = ks * 32 + ((l >> 4) << 3) + i;
  wsP[base + local] = (unsigned short)f2bf(src[row * K + k]);
}

// stage one mail panel chunk: 8 mem_input floats (already in regs) + 8 cos feats
__device__ __forceinline__ void stage_write(
    unsigned short* sAp, const float* sTs, const float* sMts,
    const float* sTeW, const float* sTeB,
    float4 f0, float4 f1, int srow, int skc, int ssw, int sg, int m)
{
  float dt = sTs[srow] - sMts[srow*10 + m];
  const float4* tw = (const float4*)(sTeW + skc);
  const float4* tb = (const float4*)(sTeB + skc);
  float4 w0 = tw[0], w1 = tw[1];
  float4 b0 = tb[0], b1 = tb[1];
  float4 c0, c1;
  c0.x=__cosf(dt*w0.x+b0.x); c0.y=__cosf(dt*w0.y+b0.y); c0.z=__cosf(dt*w0.z+b0.z); c0.w=__cosf(dt*w0.w+b0.w);
  c1.x=__cosf(dt*w1.x+b1.x); c1.y=__cosf(dt*w1.y+b1.y); c1.z=__cosf(dt*w1.z+b1.z); c1.w=__cosf(dt*w1.w+b1.w);
  bf16x8* dst = (bf16x8*)sAp;
  dst[srow*32 + (sg ^ ssw)]      = pack8(f0, f1);
  dst[srow*32 + 16 + (sg ^ ssw)] = pack8(c0, c1);  // == (16+sg)^ssw since ssw<8
}

// Persistent grid (R15, -7.5%) + cross-tile pipelined prologue: tile t+1's
// global loads and sTs/sMts/panel-1 staging are issued during tile t's
// LN/MLP epilogue, hiding the prologue latency. One extra barrier (B5) at
// loop end guards MLP's panel-0 reads vs next tile's mail-0 staging; next
// tile's B1 is eliminated (net barrier count unchanged).
// Seam audit: old sTs/sMts/panel-1 readers all precede the m-loop's final
// barrier; B4+B5 order all next-tile staging before its readers.
__global__ __launch_bounds__(512, 2) void fused_tmu(
    const float* __restrict__ mem, const float* __restrict__ mem_input,
    const float* __restrict__ ts, const float* __restrict__ mail_ts,
    const float* __restrict__ wq_b, const float* __restrict__ wk_b,
    const float* __restrict__ wv_b, const float* __restrict__ ln_g,
    const float* __restrict__ ln_b, const float* __restrict__ mlp_b,
    const float* __restrict__ te_w, const float* __restrict__ te_b,
    const unsigned short* __restrict__ wsP, float* __restrict__ out)
{
  __shared__ __align__(16) unsigned short sA[2 * NB * 256]; // two swizzled panels
  __shared__ float sTs[NB];
  __shared__ float sMts[NB * 10];
  __shared__ float sTeW[128], sTeB[128];
  __shared__ float sRed[NB * 16];

  const int tid  = threadIdx.x;
  const int lane = tid & 63;
  const int wid  = tid >> 6;         // 0..7 == head
  const int l15  = lane & 15;
  const int lg   = lane >> 4;

  const int srow = tid >> 4;         // staging row 0..31 (16 threads/row)
  const int sg   = tid & 15;         // staging granule 0..15
  const int skc  = sg << 3;          // float col base
  const int ssw  = srow & 7;

  // ---- block-invariant setup
  if (tid < 128){ sTeW[tid] = te_w[tid]; sTeB[tid] = te_b[tid]; }

  const int c = wid * 16 + l15;
  float qb = wq_b[c], kb = wk_b[c], vb = wv_b[c];
  float lgv = ln_g[c], lbv = ln_b[c], mbv = mlp_b[c];

  const bf16x8* wsv = (const bf16x8*)wsP;
  bf16x8 wkf[8], wvf[8];
  #pragma unroll
  for (int ks = 0; ks < 8; ks++){
    wkf[ks] = wsv[WKP/8 + (ks*8 + wid)*64 + lane];
    wvf[ks] = wsv[WVP/8 + (ks*8 + wid)*64 + lane];
  }

  f32x4 z4 = {0.f, 0.f, 0.f, 0.f};

  // ---- pre-loop prologue for the FIRST tile
  int tb = blockIdx.x;
  float4 fa0, fa1;   // mail-0 (then mail m+1) data, carried across barriers
  {
    const int node0 = tb * NB;
    const int sgn = imin(node0 + srow, N_NODES - 1);
    float4 fm0, fm1;
    {
      const float4* mp = (const float4*)(mem + (size_t)sgn * 128 + skc);
      fm0 = mp[0]; fm1 = mp[1];
      const float4* mi0 = (const float4*)(mem_input + (size_t)sgn * 1280 + skc);
      fa0 = mi0[0]; fa1 = mi0[1];
    }
    if (tid < NB) sTs[tid] = ts[imin(node0 + tid, N_NODES - 1)];
    if (tid < NB * 10){
      int nn = tid / 10, mm = tid - nn * 10;
      sMts[tid] = mail_ts[(size_t)imin(node0 + nn, N_NODES - 1) * 10 + mm];
    }
    bf16x8* dst = (bf16x8*)sA;
    dst[NB*32 + srow*32 + (sg ^ ssw)] = pack8(fm0, fm1);
  }
  __syncthreads();   // B1 (once): sTs/sMts/te + panel 1 ready

  for (; tb < NTILES; tb += PGRID){
    const int node0 = tb * NB;
    const int sgn = imin(node0 + srow, N_NODES - 1);
    const float* miBase = mem_input + (size_t)sgn * 1280 + skc;

    // stage mail 0 into panel 0 (fa holds mail-0 data); issue mail-1 loads
    stage_write(sA, sTs, sMts, sTeW, sTeB, fa0, fa1, srow, skc, ssw, sg, 0);
    { const float4* mi1 = (const float4*)(miBase + 128); fa0 = mi1[0]; fa1 = mi1[1]; }

    // ---- Q GEMM from panel 1 (qb folded via init)
    bf16x8 wqf[4];
    #pragma unroll
    for (int ks = 0; ks < 4; ks++)
      wqf[ks] = wsv[WQP/8 + (ks*8 + wid)*64 + lane];
    f32x4 qac[2];
    qac[0] = (f32x4){qb, qb, qb, qb};
    qac[1] = qac[0];
    {
      const bf16x8* P1 = (const bf16x8*)sA + NB*32;
      #pragma unroll
      for (int ntr = 0; ntr < 2; ntr++){
        int r = ntr*16 + l15, rs = r & 7;
        #pragma unroll
        for (int ks = 0; ks < 4; ks++){
          bf16x8 af = P1[r*32 + ((ks*4 + lg) ^ rs)];
          qac[ntr] = __builtin_amdgcn_mfma_f32_16x16x32_bf16(af, wqf[ks], qac[ntr], 0, 0, 0);
        }
      }
    }

    __syncthreads();   // B2: panel 0 ready

    // ---- fused m-loop: compute m -> stage m+1 -> prefetch m+2 -> barrier
    f32x4 pv[2] = {z4, z4};
    f32x4 sm[2] = {z4, z4};
    for (int m = 0; m < 10; m++){
      const bf16x8* P = (const bf16x8*)sA + (m & 1) * NB*32;
      #pragma unroll
      for (int ntr = 0; ntr < 2; ntr++){
        int r = ntr*16 + l15, rs = r & 7;
        f32x4 ka = z4, va = z4;
        #pragma unroll
        for (int ks = 0; ks < 8; ks++){
          bf16x8 af = P[r*32 + ((ks*4 + lg) ^ rs)];
          ka = __builtin_amdgcn_mfma_f32_16x16x32_bf16(af, wkf[ks], ka, 0, 0, 0);
          va = __builtin_amdgcn_mfma_f32_16x16x32_bf16(af, wvf[ks], va, 0, 0, 0);
        }
        #pragma unroll
        for (int j = 0; j < 4; j++){
          float lv = (ka[j] + kb) * qac[ntr][j];
          lv = rsum16_dpp(lv);
          lv = fmaxf(lv, SLOPE * lv);
          lv = fminf(lv, 60.f);
          float p = __expf(lv);
          sm[ntr][j] += p;
          pv[ntr][j] += p * va[j];
        }
      }
      if (m < 9){
        stage_write(sA + ((m+1) & 1) * NB*256, sTs, sMts, sTeW, sTeB,
                    fa0, fa1, srow, skc, ssw, sg, m+1);
        if (m < 8){
          const float4* mi = (const float4*)(miBase + (size_t)(m+2)*128);
          fa0 = mi[0]; fa1 = mi[1];
        }
      }
      __syncthreads();
    }
    // after this barrier: panels + sTs/sMts have no remaining readers

    // ---- epilogue (+ pipelined next-tile prologue)
    const int tn = tb + PGRID;
    const bool has_next = tn < NTILES;       // block-uniform
    const int node0n = tn * NB;
    const int sgnn = imin(node0n + srow, N_NODES - 1);

    float rstv[2][4];
    #pragma unroll
    for (int ntr = 0; ntr < 2; ntr++)
      #pragma unroll
      for (int j = 0; j < 4; j++){
        int gn = imin(node0 + ntr*16 + lg*4 + j, N_NODES - 1);
        rstv[ntr][j] = pv[ntr][j] / sm[ntr][j] + vb + mem[(size_t)gn * 128 + c];
      }

    // issue next-tile mem-granule loads (pv/sm regs just freed)
    float4 nf0, nf1;
    if (has_next){
      const float4* mp = (const float4*)(mem + (size_t)sgnn * 128 + skc);
      nf0 = mp[0]; nf1 = mp[1];
    }

    #pragma unroll
    for (int ntr = 0; ntr < 2; ntr++)
      #pragma unroll
      for (int j = 0; j < 4; j++){
        float s = rsum16_dpp(rstv[ntr][j]);
        float q = rsum16_dpp(rstv[ntr][j] * rstv[ntr][j]);
        if (l15 == 0){
          int nl = ntr*16 + lg*4 + j;
          sRed[nl*16 + wid*2    ] = s;
          sRed[nl*16 + wid*2 + 1] = q;
        }
      }
    __syncthreads();   // B3

    // LN finish -> y -> panel 0
    #pragma unroll
    for (int ntr = 0; ntr < 2; ntr++)
      #pragma unroll
      for (int j = 0; j < 4; j++){
        int nl = ntr*16 + lg*4 + j;
        float sum = 0.f, sq = 0.f;
        #pragma unroll
        for (int w = 0; w < 8; w++){
          sum += sRed[nl*16 + w*2];
          sq  += sRed[nl*16 + w*2 + 1];
        }
        float mu  = sum * (1.f/128.f);
        float var = sq * (1.f/128.f) - mu*mu;
        float rs  = rsqrtf(var + LN_EPS);
        float y = (rstv[ntr][j] - mu) * rs * lgv + lbv;
        sA[nl*256 + ((c >> 3) ^ (nl & 7))*8 + (c & 7)] = (unsigned short)f2bf(y);
      }

    // next-tile sTs/sMts/panel-1 staging (old readers all pre-m-loop-end)
    if (has_next){
      if (tid < NB) sTs[tid] = ts[imin(node0n + tid, N_NODES - 1)];
      if (tid < NB * 10){
        int nn = tid / 10, mm = tid - nn * 10;
        sMts[tid] = mail_ts[(size_t)imin(node0n + nn, N_NODES - 1) * 10 + mm];
      }
      bf16x8* dst = (bf16x8*)sA;
      dst[NB*32 + srow*32 + (sg ^ ssw)] = pack8(nf0, nf1);
    }

    bf16x8 mlpf[4];
    #pragma unroll
    for (int ks = 0; ks < 4; ks++)
      mlpf[ks] = wsv[MLPP/8 + (ks*8 + wid)*64 + lane];
    __syncthreads();   // B4: y(panel0) + next-tile staging visible

    // issue next-tile mail-0 loads (consumed at next loop top, after B5)
    if (has_next){
      const float4* mi0 = (const float4*)(mem_input + (size_t)sgnn * 1280 + skc);
      fa0 = mi0[0]; fa1 = mi0[1];
    }

    // ---- MLP GEMM + ReLU + store (A = LN output in panel 0; mbv folded)
    f32x4 mac[2];
    mac[0] = (f32x4){mbv, mbv, mbv, mbv};
    mac[1] = mac[0];
    {
      const bf16x8* P0 = (const bf16x8*)sA;
      #pragma unroll
      for (int ntr = 0; ntr < 2; ntr++){
        int r = ntr*16 + l15, rs = r & 7;
        #pragma unroll
        for (int ks = 0; ks < 4; ks++){
          bf16x8 af = P0[r*32 + ((ks*4 + lg) ^ rs)];
          mac[ntr] = __builtin_amdgcn_mfma_f32_16x16x32_bf16(af, mlpf[ks], mac[ntr], 0, 0, 0);
        }
      }
    }
    #pragma unroll
    for (int ntr = 0; ntr < 2; ntr++)
      #pragma unroll
      for (int j = 0; j < 4; j++){
        float o = fmaxf(mac[ntr][j], 0.f);
        int node = node0 + ntr*16 + lg*4 + j;
        if (node < N_NODES)
          out[(size_t)node * 128 + c] = o;
      }
    __syncthreads();   // B5: MLP panel-0 reads done before next mail-0 staging
  }
}

extern "C" void kernel_launch(void* const* d_in, const int* in_sizes, int n_in,
                              void* d_out, int out_size, void* d_ws, size_t ws_size,
                              hipStream_t stream)
{
  const float* mem       = (const float*)d_in[0];
  const float* mem_input = (const float*)d_in[1];
  const float* ts        = (const float*)d_in[2];
  const float* mail_ts   = (const float*)d_in[3];
  const float* wq_w      = (const float*)d_in[4];
  const float* wq_b      = (const float*)d_in[5];
  const float* wk_w      = (const float*)d_in[6];
  const float* wk_b      = (const float*)d_in[7];
  const float* wv_w      = (const float*)d_in[8];
  const float* wv_b      = (const float*)d_in[9];
  const float* ln_g      = (const float*)d_in[10];
  const float* ln_b      = (const float*)d_in[11];
  const float* mlp_w     = (const float*)d_in[12];
  const float* mlp_b     = (const float*)d_in[13];
  const float* te_w      = (const float*)d_in[14];
  const float* te_b      = (const float*)d_in[15];
  unsigned short* wsP = (unsigned short*)d_ws;
  float* outp = (float*)d_out;

  prep_pack<<<384, 256, 0, stream>>>(wq_w, wk_w, wv_w, mlp_w, wsP);
  fused_tmu<<<PGRID, 512, 0, stream>>>(mem, mem_input, ts, mail_ts,
      wq_b, wk_b, wv_b, ln_g, ln_b, mlp_b, te_w, te_b, wsP, outp);
}